// Round 8
// baseline (181.647 us; speedup 1.0000x reference)
//
#include <hip/hip_runtime.h>
#include <hip/hip_bf16.h>
#include <cstdint>
#include <cstddef>

// Problem shape (fixed): x [B=16][N=2048][D=512] fp32
#define BB 16
#define NN 2048
#define DD 512

typedef _Float16 f16x8 __attribute__((ext_vector_type(8)));
typedef _Float16 f16x4 __attribute__((ext_vector_type(4)));
typedef float f32x4 __attribute__((ext_vector_type(4)));
typedef unsigned int u32x4 __attribute__((ext_vector_type(4)));

// Async global->LDS, 16 B per lane. LDS dest = wave-uniform base + lane*16.
__device__ __forceinline__ void async_ld16(void* lds, const void* g) {
    __builtin_amdgcn_global_load_lds(
        (const __attribute__((address_space(1))) unsigned int*)(uintptr_t)g,
        (__attribute__((address_space(3))) unsigned int*)(uint32_t)(uintptr_t)lds,
        16, 0, 0);
}
// NT variant (aux=2 = NT/SLC CPol bit): stream-once data, evict-first in L2/L3.
__device__ __forceinline__ void async_ld16_nt(void* lds, const void* g) {
    __builtin_amdgcn_global_load_lds(
        (const __attribute__((address_space(1))) unsigned int*)(uintptr_t)g,
        (__attribute__((address_space(3))) unsigned int*)(uint32_t)(uintptr_t)lds,
        16, 0, 2);
}

#define VM_WAIT(n) asm volatile("s_waitcnt vmcnt(" #n ")" ::: "memory")
#define RAW_BAR()  do { asm volatile("" ::: "memory"); __builtin_amdgcn_s_barrier(); asm volatile("" ::: "memory"); } while (0)
// LDS-order-only barrier: global stores/atomics keep draining.
#define LGKM_BAR() do { asm volatile("s_waitcnt lgkmcnt(0)" ::: "memory"); \
                        __builtin_amdgcn_s_barrier();                      \
                        __builtin_amdgcn_sched_barrier(0); } while (0)
// Wait own ds_reads, then fence the scheduler (rule #18: MFMA must not hoist).
#define LGKM0_FENCE() do { asm volatile("s_waitcnt lgkmcnt(0)" ::: "memory"); \
                           __builtin_amdgcn_sched_barrier(0); } while (0)

// ---------------------------------------------------------------------------
// K1 (fused): read x ONCE (non-temporal: x is stream-once; protect the
// xhn/vT we are writing from L3 eviction). Per 64-row slab: norms,
// xhn (normalized fp16), vT (fp16 transpose), denom zero-init.
// grid (NN/64, BB), 256 threads.
// ---------------------------------------------------------------------------
__global__ __launch_bounds__(256) void k_prep(const float* __restrict__ x,
                                              _Float16* __restrict__ xhn,
                                              _Float16* __restrict__ vT,
                                              float* __restrict__ denom) {
    __shared__ _Float16 t[512 * 66];     // [d][j], pitch 66 halves
    const int tid = threadIdx.x, lane = tid & 63, w = tid >> 6;
    const int b = blockIdx.y, j0 = blockIdx.x * 64;
    if (tid < 64) denom[b * NN + j0 + tid] = 0.f;
    const float* xb = x + ((size_t)b * NN + j0) * DD;

    for (int rr = 0; rr < 16; ++rr) {
        const int jj = w * 16 + rr;                 // row within slab
        const float* xr = xb + (size_t)jj * DD;
        f32x4 a = __builtin_nontemporal_load((const f32x4*)xr + lane);
        f32x4 c = __builtin_nontemporal_load((const f32x4*)xr + lane + 64);
        float ss = a[0]*a[0] + a[1]*a[1] + a[2]*a[2] + a[3]*a[3]
                 + c[0]*c[0] + c[1]*c[1] + c[2]*c[2] + c[3]*c[3];
        #pragma unroll
        for (int o = 1; o < 64; o <<= 1) ss += __shfl_xor(ss, o);
        const float rn = 1.0f / sqrtf(ss);
        // normalized fp16 row (coalesced 8B stores)
        _Float16* dst = xhn + ((size_t)b * NN + j0 + jj) * DD;
        f16x4 v0 = {(_Float16)(a[0]*rn), (_Float16)(a[1]*rn), (_Float16)(a[2]*rn), (_Float16)(a[3]*rn)};
        f16x4 v1 = {(_Float16)(c[0]*rn), (_Float16)(c[1]*rn), (_Float16)(c[2]*rn), (_Float16)(c[3]*rn)};
        *(f16x4*)(dst + 4 * lane) = v0;
        *(f16x4*)(dst + 256 + 4 * lane) = v1;
        // unnormalized fp16 into transposed LDS tile
        const int d0 = 4 * lane, d1 = 256 + 4 * lane;
        t[(d0 + 0) * 66 + jj] = (_Float16)a[0];
        t[(d0 + 1) * 66 + jj] = (_Float16)a[1];
        t[(d0 + 2) * 66 + jj] = (_Float16)a[2];
        t[(d0 + 3) * 66 + jj] = (_Float16)a[3];
        t[(d1 + 0) * 66 + jj] = (_Float16)c[0];
        t[(d1 + 1) * 66 + jj] = (_Float16)c[1];
        t[(d1 + 2) * 66 + jj] = (_Float16)c[2];
        t[(d1 + 3) * 66 + jj] = (_Float16)c[3];
    }
    LGKM_BAR();   // xhn global stores keep draining under the vT phase
    // store vT rows: 512 d x 8 chunks of 8 halves; 4B-aligned b32 LDS reads.
    #pragma unroll
    for (int it = 0; it < 16; ++it) {
        const int id = it * 256 + tid;
        const int d = id >> 3, ch = (id & 7) * 8;
        const uint32_t* tp = (const uint32_t*)&t[d * 66 + ch];
        uint4 v = {tp[0], tp[1], tp[2], tp[3]};
        *(uint4*)(vT + ((size_t)b * DD + d) * NN + j0 + ch) = v;
    }
}

// ---------------------------------------------------------------------------
// K2: W = exp( xhn xhn^T ), symmetric-triangular. 128x128 block, 4 waves,
// single-buffered BK=64, 34 KiB LDS -> 4 blocks/CU, XCD tile-pair swizzle.
// NEW this round: W stores are NON-TEMPORAL (stream-once, 140 MB): stop the
// store stream from evicting the 32 MB xhn working set out of L3
// (FETCH_SIZE was 100 MB vs 32 MB compulsory -> expect ~40-55 MB).
// ---------------------------------------------------------------------------
__global__ __launch_bounds__(256, 4) void k_scores(const _Float16* __restrict__ xhn,
                                                   _Float16* __restrict__ W,
                                                   float* __restrict__ denom) {
    __shared__ _Float16 smem[17408];          // As[8192]+Bs[8192]; epi: 128x136
    const int tid = threadIdx.x;
    const int lane = tid & 63, wv = tid >> 6;
    const int wr = wv >> 1, wc = wv & 1;
    const int m_ = lane & 15, quad = lane >> 4;
    const int b = blockIdx.z;

    // XCD swizzle: 136 = 8 * 17 -> each XCD gets 17 consecutive pairs.
    const int swz = (blockIdx.x % 8) * 17 + blockIdx.x / 8;
    int rem = swz, ti = 0, rowlen = NN / 128;
    while (rem >= rowlen) { rem -= rowlen; ++ti; --rowlen; }
    const int tj = ti + rem;
    const int I = ti * 128, J = tj * 128;
    const bool diag = (ti == tj);

    const _Float16* Ab = xhn + ((size_t)b * NN + I) * DD;
    const _Float16* Bb = xhn + ((size_t)b * NN + J) * DD;

    f32x4 acc[4][4];
    #pragma unroll
    for (int i = 0; i < 4; ++i)
        #pragma unroll
        for (int j = 0; j < 4; ++j) acc[i][j] = (f32x4){0.f, 0.f, 0.f, 0.f};

    const int sub = lane >> 3;
    const int swc = (lane & 7) ^ sub;
    const _Float16* agl = Ab + (size_t)(wv * 32 + sub) * DD + swc * 8;
    const _Float16* bgl = Bb + (size_t)(wv * 32 + sub) * DD + swc * 8;
    _Float16* As = smem;
    _Float16* Bs = smem + 8192;

    for (int kb = 0; kb < DD / 64; ++kb) {
        const int k0 = kb * 64;
        #pragma unroll
        for (int c = 0; c < 4; ++c) {
            async_ld16(&As[(wv * 32 + c * 8) * 64], agl + (size_t)c * 8 * DD + k0);
            async_ld16(&Bs[(wv * 32 + c * 8) * 64], bgl + (size_t)c * 8 * DD + k0);
        }
        VM_WAIT(0);
        RAW_BAR();
        __builtin_amdgcn_s_setprio(1);
        #pragma unroll
        for (int kc = 0; kc < 2; ++kc) {
            f16x8 af[4], bf[4];
            #pragma unroll
            for (int t = 0; t < 4; ++t) {
                const int Ra = wr * 64 + t * 16 + m_;
                const int Rb = wc * 64 + t * 16 + m_;
                af[t] = *(const f16x8*)&As[Ra * 64 + (((kc * 4 + quad) ^ (Ra & 7)) * 8)];
                bf[t] = *(const f16x8*)&Bs[Rb * 64 + (((kc * 4 + quad) ^ (Rb & 7)) * 8)];
            }
            #pragma unroll
            for (int i = 0; i < 4; ++i)
                #pragma unroll
                for (int j = 0; j < 4; ++j)
                    acc[i][j] = __builtin_amdgcn_mfma_f32_16x16x32_f16(af[i], bf[j], acc[i][j], 0, 0, 0);
        }
        __builtin_amdgcn_s_setprio(0);
        RAW_BAR();   // all waves done reading before next stage overwrites
    }

    // Epilogue: exp into packed f16x4; register row/col sums.
    f16x4 wq[4][4];
    float rowpart[4][4];
    float colpart[4] = {0.f, 0.f, 0.f, 0.f};
    #pragma unroll
    for (int i = 0; i < 4; ++i)
        #pragma unroll
        for (int r = 0; r < 4; ++r) rowpart[i][r] = 0.f;

    #pragma unroll
    for (int i = 0; i < 4; ++i) {
        #pragma unroll
        for (int j = 0; j < 4; ++j) {
            #pragma unroll
            for (int r = 0; r < 4; ++r) {
                const float w = __expf(acc[i][j][r]);
                wq[i][j][r] = (_Float16)w;
                rowpart[i][r] += w;
                colpart[j] += w;
            }
        }
    }

    #pragma unroll
    for (int i = 0; i < 4; ++i) {
        #pragma unroll
        for (int r = 0; r < 4; ++r) {
            float s = rowpart[i][r];
            s += __shfl_xor(s, 1);
            s += __shfl_xor(s, 2);
            s += __shfl_xor(s, 4);
            s += __shfl_xor(s, 8);
            if (m_ == 0)
                atomicAdd(&denom[b * NN + I + wr * 64 + i * 16 + quad * 4 + r], s);
        }
    }
    if (!diag) {
        #pragma unroll
        for (int j = 0; j < 4; ++j) {
            float s = colpart[j];
            s += __shfl_xor(s, 16);
            s += __shfl_xor(s, 32);
            if (quad == 0)
                atomicAdd(&denom[b * NN + J + wc * 64 + j * 16 + m_], s);
        }
    }

    LGKM_BAR();   // LDS ordering only: atomics keep draining

    // Phase 1: WtT[col][row] (stride 136), b64 writes -> coalesced W(J,I).
    _Float16* WtT = smem;
    #pragma unroll
    for (int i = 0; i < 4; ++i) {
        const int rowb = wr * 64 + i * 16 + quad * 4;
        #pragma unroll
        for (int j = 0; j < 4; ++j) {
            const int col = wc * 64 + j * 16 + m_;
            *(f16x4*)&WtT[col * 136 + rowb] = wq[i][j];
        }
    }
    LGKM_BAR();
    // lane-coalesced NT store: 16 lanes = one contiguous 256 B row segment.
    #pragma unroll
    for (int it2 = 0; it2 < 8; ++it2) {
        const int id = it2 * 256 + tid;
        const int rr = id >> 4, off = (id & 15) * 8;
        __builtin_nontemporal_store(
            *(const u32x4*)&WtT[rr * 136 + off],
            (u32x4*)(W + ((size_t)b * NN + J + rr) * NN + I + off));
    }
    // Phase 2 (off-diag): row-major Wt -> coalesced W(I,J).
    if (!diag) {
        LGKM_BAR();   // phase-1 LDS reads done; W(J,I) stores still in flight
        _Float16* Wt = smem;
        #pragma unroll
        for (int i = 0; i < 4; ++i) {
            const int rowb = wr * 64 + i * 16 + quad * 4;
            #pragma unroll
            for (int j = 0; j < 4; ++j) {
                const int col = wc * 64 + j * 16 + m_;
                #pragma unroll
                for (int r = 0; r < 4; ++r)
                    Wt[(rowb + r) * 136 + col] = wq[i][j][r];
            }
        }
        LGKM_BAR();
        #pragma unroll
        for (int it2 = 0; it2 < 8; ++it2) {
            const int id = it2 * 256 + tid;
            const int rr = id >> 4, off = (id & 15) * 8;
            __builtin_nontemporal_store(
                *(const u32x4*)&Wt[rr * 136 + off],
                (u32x4*)(W + ((size_t)b * NN + I + rr) * NN + J + off));
        }
    }
}

// ---------------------------------------------------------------------------
// K3: O = (W @ V) * (1/denom_i), fp32 out.
// 256x256 tile, 8 waves 2Mx4N, BK=64, 128 KiB ring-2 dbuf, XCD batch-pin,
// fine per-phase stage interleave (R7).
// NEW: W staging loads NT (134 MB stream-once -> evict-first, keeps the
// 8x-reused 2 MiB vT panels L3/L2-resident); out stores NT (64 MB,
// never re-read).
// ---------------------------------------------------------------------------
__global__ __launch_bounds__(512, 2) void k_pv(const _Float16* __restrict__ W,
                                               const _Float16* __restrict__ vT,
                                               const float* __restrict__ denom,
                                               float* __restrict__ out) {
    extern __shared__ _Float16 smem[];        // 2 x (A 16384 + B 16384) halves = 128 KiB
    float* rdI = (float*)(smem + 65536);      // 256 floats after the buffers
    const int tid = threadIdx.x;
    const int lane = tid & 63, w = tid >> 6;  // 8 waves
    const int wr = w >> 2, wcol = w & 3;      // 2 x 4 wave grid
    const int m_ = lane & 15, quad = lane >> 4;

    // XCD pinning: bx -> (xcd, slot); b = (slot>>4)*8 + xcd; I,d from slot.
    const int bx = blockIdx.x;
    const int xcd = bx & 7, slot = bx >> 3;
    const int b  = (slot >> 4) * 8 + xcd;
    const int I  = ((slot >> 1) & 7) * 256;
    const int D0 = (slot & 1) * 256;

    const _Float16* Ab = W  + ((size_t)b * NN + I) * NN;
    const _Float16* Bb = vT + ((size_t)b * DD + D0) * NN;

    const int sub = lane >> 3;
    const int swc = (lane & 7) ^ sub;
    const _Float16* agl = Ab + (size_t)(w * 32 + sub) * NN + swc * 8;
    const _Float16* bgl = Bb + (size_t)(w * 32 + sub) * NN + swc * 8;

    f32x4 acc[8][4];
    #pragma unroll
    for (int i = 0; i < 8; ++i)
        #pragma unroll
        for (int j = 0; j < 4; ++j) acc[i][j] = (f32x4){0.f, 0.f, 0.f, 0.f};

    f16x8 afq[4][2];   // current i-quadrant A frags (kc 0,1)
    f16x8 bfq[4][2];   // all four j B frags (kc 0,1)

    const int NT = NN / 64;

// Stage one chunk pair of tile kb_ (A chunk NT from W stream, B chunk cached vT).
#define P_PART(kb_, c_) do {                                                  \
    _Float16* A_ = smem + (((kb_) & 1) << 15);                                \
    const int k0_ = (kb_) * 64;                                               \
    async_ld16_nt(&A_[(w * 32 + (c_) * 8) * 64], agl + (size_t)(c_) * 8 * NN + k0_); \
    async_ld16(&A_[16384 + (w * 32 + (c_) * 8) * 64], bgl + (size_t)(c_) * 8 * NN + k0_); \
    } while (0)

#define LD_A(t_, ih_) do {                                                    \
    const int R = wr * 128 + ((ih_) * 4 + (t_)) * 16 + m_;                    \
    afq[t_][0] = *(const f16x8*)&As_[R * 64 + ((quad ^ (R & 7)) * 8)];        \
    afq[t_][1] = *(const f16x8*)&As_[R * 64 + (((4 + quad) ^ (R & 7)) * 8)];  \
    } while (0)

#define LD_B(j_) do {                                                         \
    const int Rb = wcol * 64 + (j_) * 16 + m_;                                \
    bfq[j_][0] = *(const f16x8*)&Bs_[Rb * 64 + ((quad ^ (Rb & 7)) * 8)];      \
    bfq[j_][1] = *(const f16x8*)&Bs_[Rb * 64 + (((4 + quad) ^ (Rb & 7)) * 8)];\
    } while (0)

#define MFMA_Q(ih_, jh_) do {                                                 \
    __builtin_amdgcn_s_setprio(1);                                            \
    _Pragma("unroll")                                                         \
    for (int t = 0; t < 4; ++t)                                               \
        _Pragma("unroll")                                                     \
        for (int j = 0; j < 2; ++j) {                                         \
            acc[(ih_)*4+t][(jh_)*2+j] = __builtin_amdgcn_mfma_f32_16x16x32_f16( \
                afq[t][0], bfq[(jh_)*2+j][0], acc[(ih_)*4+t][(jh_)*2+j], 0, 0, 0); \
            acc[(ih_)*4+t][(jh_)*2+j] = __builtin_amdgcn_mfma_f32_16x16x32_f16( \
                afq[t][1], bfq[(jh_)*2+j][1], acc[(ih_)*4+t][(jh_)*2+j], 0, 0, 0); \
        }                                                                     \
    __builtin_amdgcn_s_setprio(0);                                            \
    } while (0)

    // Prologue: steady-state image at t=0: stage(0) fully issued,
    // stage(1) chunks c0,c1 issued.
    P_PART(0, 0); P_PART(0, 1); P_PART(0, 2); P_PART(0, 3);
    P_PART(1, 0); P_PART(1, 1);

    for (int tc = 0; tc < NT; ++tc) {
        const _Float16* As_ = smem + ((tc & 1) << 15);
        const _Float16* Bs_ = As_ + 16384;
        if (tc == NT - 1) { VM_WAIT(0); } else { VM_WAIT(4); }
        RAW_BAR();
        // ---- P0: quadrant (0,0). ds: af[0..3] + bf[0..1]; stage(t+1) c2
        #pragma unroll
        for (int t = 0; t < 4; ++t) LD_A(t, 0);
        LD_B(0); LD_B(1);
        if (tc + 1 < NT) P_PART(tc + 1, 2);
        RAW_BAR();
        LGKM0_FENCE();
        MFMA_Q(0, 0);
        RAW_BAR();
        // ---- P1: quadrant (0,1). ds: bf[2..3]; stage(t+1) c3
        LD_B(2); LD_B(3);
        if (tc + 1 < NT) P_PART(tc + 1, 3);
        RAW_BAR();
        LGKM0_FENCE();
        MFMA_Q(0, 1);
        RAW_BAR();
        // ---- P2: quadrant (1,0). ds: af[4..7]
        #pragma unroll
        for (int t = 0; t < 4; ++t) LD_A(t, 1);
        RAW_BAR();
        LGKM0_FENCE();
        MFMA_Q(1, 0);
        RAW_BAR();
        // ---- P3: quadrant (1,1). current buffer's reads done -> stage(t+2) c0,c1
        if (tc + 2 < NT) { P_PART(tc + 2, 0); P_PART(tc + 2, 1); }
        RAW_BAR();
        MFMA_Q(1, 1);
        RAW_BAR();
    }

    // Epilogue: per-row reciprocal denominators via LDS broadcast, then store.
    if (tid < 256) rdI[tid] = 1.0f / denom[b * NN + I + tid];
    LGKM_BAR();

    #pragma unroll
    for (int i = 0; i < 8; ++i) {
        const int rowb = wr * 128 + i * 16 + quad * 4;
        #pragma unroll
        for (int r = 0; r < 4; ++r) {
            const float sc = rdI[rowb + r];
            float* op = out + ((size_t)(b * NN + I + rowb + r)) * DD + D0;
            #pragma unroll
            for (int j = 0; j < 4; ++j)
                __builtin_nontemporal_store(acc[i][j][r] * sc,
                                            op + wcol * 64 + j * 16 + m_);
        }
    }
#undef P_PART
#undef LD_A
#undef LD_B
#undef MFMA_Q
}

// ---------------------------------------------------------------------------
extern "C" void kernel_launch(void* const* d_in, const int* in_sizes, int n_in,
                              void* d_out, int out_size, void* d_ws, size_t ws_size,
                              hipStream_t stream) {
    const float* x = (const float*)d_in[0];
    char* ws = (char*)d_ws;
    _Float16* xhn   = (_Float16*)(ws);                        // 32 MiB normalized fp16
    _Float16* vT    = (_Float16*)(ws + (size_t)33554432);     // 32 MiB fp16 x^T
    _Float16* W     = (_Float16*)(ws + (size_t)67108864);     // 128 MiB fp16 exp-scores
    float*    denom = (float*)   (ws + (size_t)201326592);    // 128 KiB
    float*    out   = (float*)d_out;

    k_prep<<<dim3(NN / 64, BB), 256, 0, stream>>>(x, xhn, vT, denom);
    const int npairs = (NN / 128) * (NN / 128 + 1) / 2;   // 136
    k_scores<<<dim3(npairs, 1, BB), 256, 0, stream>>>(xhn, W, denom);
    // flat 256-block grid, XCD batch-pinned; 128 KiB dbuf + 1 KiB rdI dynamic
    k_pv<<<dim3(256, 1, 1), 512, 132096, stream>>>(W, vT, denom, out);
}

// Round 11
// 175.380 us; speedup vs baseline: 1.0357x; 1.0357x over previous
//
#include <hip/hip_runtime.h>
#include <hip/hip_bf16.h>
#include <cstdint>
#include <cstddef>

// Problem shape (fixed): x [B=16][N=2048][D=512] fp32
#define BB 16
#define NN 2048
#define DD 512

typedef _Float16 f16x8 __attribute__((ext_vector_type(8)));
typedef _Float16 f16x4 __attribute__((ext_vector_type(4)));
typedef float f32x4 __attribute__((ext_vector_type(4)));
typedef unsigned int u32x4 __attribute__((ext_vector_type(4)));

// Async global->LDS, 16 B per lane. LDS dest = wave-uniform base + lane*16.
__device__ __forceinline__ void async_ld16(void* lds, const void* g) {
    __builtin_amdgcn_global_load_lds(
        (const __attribute__((address_space(1))) unsigned int*)(uintptr_t)g,
        (__attribute__((address_space(3))) unsigned int*)(uint32_t)(uintptr_t)lds,
        16, 0, 0);
}

#define VM_WAIT(n) asm volatile("s_waitcnt vmcnt(" #n ")" ::: "memory")
#define RAW_BAR()  do { asm volatile("" ::: "memory"); __builtin_amdgcn_s_barrier(); asm volatile("" ::: "memory"); } while (0)
// LDS-order-only barrier: global stores/atomics keep draining.
#define LGKM_BAR() do { asm volatile("s_waitcnt lgkmcnt(0)" ::: "memory"); \
                        __builtin_amdgcn_s_barrier();                      \
                        __builtin_amdgcn_sched_barrier(0); } while (0)

// ---------------------------------------------------------------------------
// K1 (fused): read x ONCE (non-temporal: stream-once). Per 64-row slab:
// norms, xhn (normalized fp16), vT (fp16 transpose), denom zero-init.
// grid (NN/64, BB), 256 threads.
// ---------------------------------------------------------------------------
__global__ __launch_bounds__(256) void k_prep(const float* __restrict__ x,
                                              _Float16* __restrict__ xhn,
                                              _Float16* __restrict__ vT,
                                              float* __restrict__ denom) {
    __shared__ _Float16 t[512 * 66];     // [d][j], pitch 66 halves
    const int tid = threadIdx.x, lane = tid & 63, w = tid >> 6;
    const int b = blockIdx.y, j0 = blockIdx.x * 64;
    if (tid < 64) denom[b * NN + j0 + tid] = 0.f;
    const float* xb = x + ((size_t)b * NN + j0) * DD;

    for (int rr = 0; rr < 16; ++rr) {
        const int jj = w * 16 + rr;                 // row within slab
        const float* xr = xb + (size_t)jj * DD;
        f32x4 a = __builtin_nontemporal_load((const f32x4*)xr + lane);
        f32x4 c = __builtin_nontemporal_load((const f32x4*)xr + lane + 64);
        float ss = a[0]*a[0] + a[1]*a[1] + a[2]*a[2] + a[3]*a[3]
                 + c[0]*c[0] + c[1]*c[1] + c[2]*c[2] + c[3]*c[3];
        #pragma unroll
        for (int o = 1; o < 64; o <<= 1) ss += __shfl_xor(ss, o);
        const float rn = 1.0f / sqrtf(ss);
        // normalized fp16 row (coalesced 8B stores)
        _Float16* dst = xhn + ((size_t)b * NN + j0 + jj) * DD;
        f16x4 v0 = {(_Float16)(a[0]*rn), (_Float16)(a[1]*rn), (_Float16)(a[2]*rn), (_Float16)(a[3]*rn)};
        f16x4 v1 = {(_Float16)(c[0]*rn), (_Float16)(c[1]*rn), (_Float16)(c[2]*rn), (_Float16)(c[3]*rn)};
        *(f16x4*)(dst + 4 * lane) = v0;
        *(f16x4*)(dst + 256 + 4 * lane) = v1;
        // unnormalized fp16 into transposed LDS tile
        const int d0 = 4 * lane, d1 = 256 + 4 * lane;
        t[(d0 + 0) * 66 + jj] = (_Float16)a[0];
        t[(d0 + 1) * 66 + jj] = (_Float16)a[1];
        t[(d0 + 2) * 66 + jj] = (_Float16)a[2];
        t[(d0 + 3) * 66 + jj] = (_Float16)a[3];
        t[(d1 + 0) * 66 + jj] = (_Float16)c[0];
        t[(d1 + 1) * 66 + jj] = (_Float16)c[1];
        t[(d1 + 2) * 66 + jj] = (_Float16)c[2];
        t[(d1 + 3) * 66 + jj] = (_Float16)c[3];
    }
    LGKM_BAR();   // xhn global stores keep draining under the vT phase
    // store vT rows: 512 d x 8 chunks of 8 halves; 4B-aligned b32 LDS reads.
    #pragma unroll
    for (int it = 0; it < 16; ++it) {
        const int id = it * 256 + tid;
        const int d = id >> 3, ch = (id & 7) * 8;
        const uint32_t* tp = (const uint32_t*)&t[d * 66 + ch];
        uint4 v = {tp[0], tp[1], tp[2], tp[3]};
        *(uint4*)(vT + ((size_t)b * DD + d) * NN + j0 + ch) = v;
    }
}

// ---------------------------------------------------------------------------
// K2: W = exp( xhn xhn^T ), symmetric-triangular. 128x128 block, 4 waves,
// single-buffered BK=64, 34 KiB LDS -> 4 blocks/CU, XCD tile-pair swizzle,
// lane-coalesced 256B-segment stores, LGKM-only epilogue barriers.
// NT W-stores REVERTED to cached (R8 post-mortem: W L3-residency for k_pv
// is worth more than xhn protection here; xhn+W = 167 MB < 256 MB L3).
// ---------------------------------------------------------------------------
__global__ __launch_bounds__(256, 4) void k_scores(const _Float16* __restrict__ xhn,
                                                   _Float16* __restrict__ W,
                                                   float* __restrict__ denom) {
    __shared__ _Float16 smem[17408];          // As[8192]+Bs[8192]; epi: 128x136
    const int tid = threadIdx.x;
    const int lane = tid & 63, wv = tid >> 6;
    const int wr = wv >> 1, wc = wv & 1;
    const int m_ = lane & 15, quad = lane >> 4;
    const int b = blockIdx.z;

    // XCD swizzle: 136 = 8 * 17 -> each XCD gets 17 consecutive pairs.
    const int swz = (blockIdx.x % 8) * 17 + blockIdx.x / 8;
    int rem = swz, ti = 0, rowlen = NN / 128;
    while (rem >= rowlen) { rem -= rowlen; ++ti; --rowlen; }
    const int tj = ti + rem;
    const int I = ti * 128, J = tj * 128;
    const bool diag = (ti == tj);

    const _Float16* Ab = xhn + ((size_t)b * NN + I) * DD;
    const _Float16* Bb = xhn + ((size_t)b * NN + J) * DD;

    f32x4 acc[4][4];
    #pragma unroll
    for (int i = 0; i < 4; ++i)
        #pragma unroll
        for (int j = 0; j < 4; ++j) acc[i][j] = (f32x4){0.f, 0.f, 0.f, 0.f};

    const int sub = lane >> 3;
    const int swc = (lane & 7) ^ sub;
    const _Float16* agl = Ab + (size_t)(wv * 32 + sub) * DD + swc * 8;
    const _Float16* bgl = Bb + (size_t)(wv * 32 + sub) * DD + swc * 8;
    _Float16* As = smem;
    _Float16* Bs = smem + 8192;

    for (int kb = 0; kb < DD / 64; ++kb) {
        const int k0 = kb * 64;
        #pragma unroll
        for (int c = 0; c < 4; ++c) {
            async_ld16(&As[(wv * 32 + c * 8) * 64], agl + (size_t)c * 8 * DD + k0);
            async_ld16(&Bs[(wv * 32 + c * 8) * 64], bgl + (size_t)c * 8 * DD + k0);
        }
        VM_WAIT(0);
        RAW_BAR();
        __builtin_amdgcn_s_setprio(1);
        #pragma unroll
        for (int kc = 0; kc < 2; ++kc) {
            f16x8 af[4], bf[4];
            #pragma unroll
            for (int t = 0; t < 4; ++t) {
                const int Ra = wr * 64 + t * 16 + m_;
                const int Rb = wc * 64 + t * 16 + m_;
                af[t] = *(const f16x8*)&As[Ra * 64 + (((kc * 4 + quad) ^ (Ra & 7)) * 8)];
                bf[t] = *(const f16x8*)&Bs[Rb * 64 + (((kc * 4 + quad) ^ (Rb & 7)) * 8)];
            }
            #pragma unroll
            for (int i = 0; i < 4; ++i)
                #pragma unroll
                for (int j = 0; j < 4; ++j)
                    acc[i][j] = __builtin_amdgcn_mfma_f32_16x16x32_f16(af[i], bf[j], acc[i][j], 0, 0, 0);
        }
        __builtin_amdgcn_s_setprio(0);
        RAW_BAR();   // all waves done reading before next stage overwrites
    }

    // Epilogue: exp into packed f16x4; register row/col sums.
    f16x4 wq[4][4];
    float rowpart[4][4];
    float colpart[4] = {0.f, 0.f, 0.f, 0.f};
    #pragma unroll
    for (int i = 0; i < 4; ++i)
        #pragma unroll
        for (int r = 0; r < 4; ++r) rowpart[i][r] = 0.f;

    #pragma unroll
    for (int i = 0; i < 4; ++i) {
        #pragma unroll
        for (int j = 0; j < 4; ++j) {
            #pragma unroll
            for (int r = 0; r < 4; ++r) {
                const float w = __expf(acc[i][j][r]);
                wq[i][j][r] = (_Float16)w;
                rowpart[i][r] += w;
                colpart[j] += w;
            }
        }
    }

    #pragma unroll
    for (int i = 0; i < 4; ++i) {
        #pragma unroll
        for (int r = 0; r < 4; ++r) {
            float s = rowpart[i][r];
            s += __shfl_xor(s, 1);
            s += __shfl_xor(s, 2);
            s += __shfl_xor(s, 4);
            s += __shfl_xor(s, 8);
            if (m_ == 0)
                atomicAdd(&denom[b * NN + I + wr * 64 + i * 16 + quad * 4 + r], s);
        }
    }
    if (!diag) {
        #pragma unroll
        for (int j = 0; j < 4; ++j) {
            float s = colpart[j];
            s += __shfl_xor(s, 16);
            s += __shfl_xor(s, 32);
            if (quad == 0)
                atomicAdd(&denom[b * NN + J + wc * 64 + j * 16 + m_], s);
        }
    }

    LGKM_BAR();   // LDS ordering only: atomics keep draining

    // Phase 1: WtT[col][row] (stride 136), b64 writes -> coalesced W(J,I).
    _Float16* WtT = smem;
    #pragma unroll
    for (int i = 0; i < 4; ++i) {
        const int rowb = wr * 64 + i * 16 + quad * 4;
        #pragma unroll
        for (int j = 0; j < 4; ++j) {
            const int col = wc * 64 + j * 16 + m_;
            *(f16x4*)&WtT[col * 136 + rowb] = wq[i][j];
        }
    }
    LGKM_BAR();
    // lane-coalesced store: 16 lanes = one contiguous 256 B row segment.
    #pragma unroll
    for (int it2 = 0; it2 < 8; ++it2) {
        const int id = it2 * 256 + tid;
        const int rr = id >> 4, off = (id & 15) * 8;
        *(uint4*)(W + ((size_t)b * NN + J + rr) * NN + I + off) =
            *(const uint4*)&WtT[rr * 136 + off];
    }
    // Phase 2 (off-diag): row-major Wt -> coalesced W(I,J).
    if (!diag) {
        LGKM_BAR();   // phase-1 LDS reads done; W(J,I) stores still in flight
        _Float16* Wt = smem;
        #pragma unroll
        for (int i = 0; i < 4; ++i) {
            const int rowb = wr * 64 + i * 16 + quad * 4;
            #pragma unroll
            for (int j = 0; j < 4; ++j) {
                const int col = wc * 64 + j * 16 + m_;
                #pragma unroll
                for (int r = 0; r < 4; ++r)
                    Wt[(rowb + r) * 136 + col] = wq[i][j][r];
            }
        }
        LGKM_BAR();
        #pragma unroll
        for (int it2 = 0; it2 < 8; ++it2) {
            const int id = it2 * 256 + tid;
            const int rr = id >> 4, off = (id & 15) * 8;
            *(uint4*)(W + ((size_t)b * NN + I + rr) * NN + J + off) =
                *(const uint4*)&Wt[rr * 136 + off];
        }
    }
}

// ---------------------------------------------------------------------------
// K3 REWRITE (R7-k_scores structure applied): O = (W @ V) * (1/denom_i).
// Tile 128(I) x 256(D), 8 waves (2Mx4N, per-wave 64x64), BK=64, SINGLE-
// buffered static LDS 48.5 KiB -> grid 512 blocks = 2 blocks/CU (was 1):
// cross-block TLP hides the per-step vmcnt(0) drain (m114 — the proven
// session mechanism; 5 intra-block scheduling attempts were null).
// W staging loads cached (L3-resident after k_scores); out stores NT.
// XCD batch-pinning kept, d-pairs adjacent (W panel L2-shared).
// ---------------------------------------------------------------------------
__global__ __launch_bounds__(512, 4) void k_pv(const _Float16* __restrict__ W,
                                               const _Float16* __restrict__ vT,
                                               const float* __restrict__ denom,
                                               float* __restrict__ out) {
    __shared__ _Float16 smem[24576];   // As[128][64]=8192h, Bs[256][64]=16384h
    __shared__ float rdI[128];
    const int tid = threadIdx.x;
    const int lane = tid & 63, w = tid >> 6;  // 8 waves
    const int wr = w >> 2, wcol = w & 3;      // 2 x 4 wave grid
    const int m_ = lane & 15, quad = lane >> 4;

    // XCD pinning: 512 blocks, 64 slots per XCD, 2 batches per XCD.
    const int bx = blockIdx.x;
    const int xcd = bx & 7, slot = bx >> 3;        // slot 0..63
    const int b  = (slot >> 5) * 8 + xcd;          // 2 batches/XCD
    const int s2 = slot & 31;                      // 32 blocks/batch
    const int I  = (s2 >> 1) * 128;                // 16 I-tiles
    const int D0 = (s2 & 1) * 256;                 // d-pairs adjacent

    const _Float16* Ab = W  + ((size_t)b * NN + I) * NN;
    const _Float16* Bb = vT + ((size_t)b * DD + D0) * NN;

    const int sub = lane >> 3;
    const int swc = (lane & 7) ^ sub;
    // A: 128 rows, wave stages 16 rows (2 chunks of 8).
    const _Float16* agl = Ab + (size_t)(w * 16 + sub) * NN + swc * 8;
    // B: 256 rows, wave stages 32 rows (4 chunks of 8).
    const _Float16* bgl = Bb + (size_t)(w * 32 + sub) * NN + swc * 8;
    _Float16* As = smem;
    _Float16* Bs = smem + 8192;

    f32x4 acc[4][4];
    #pragma unroll
    for (int i = 0; i < 4; ++i)
        #pragma unroll
        for (int j = 0; j < 4; ++j) acc[i][j] = (f32x4){0.f, 0.f, 0.f, 0.f};

    for (int kb = 0; kb < NN / 64; ++kb) {
        const int k0 = kb * 64;
        #pragma unroll
        for (int c = 0; c < 2; ++c)
            async_ld16(&As[(w * 16 + c * 8) * 64], agl + (size_t)c * 8 * NN + k0);
        #pragma unroll
        for (int c = 0; c < 4; ++c)
            async_ld16(&Bs[(w * 32 + c * 8) * 64], bgl + (size_t)c * 8 * NN + k0);
        VM_WAIT(0);
        RAW_BAR();
        __builtin_amdgcn_s_setprio(1);
        #pragma unroll
        for (int kc = 0; kc < 2; ++kc) {
            f16x8 af[4], bf[4];
            #pragma unroll
            for (int t = 0; t < 4; ++t) {
                const int Ra = wr * 64 + t * 16 + m_;
                const int Rb = wcol * 64 + t * 16 + m_;
                af[t] = *(const f16x8*)&As[Ra * 64 + (((kc * 4 + quad) ^ (Ra & 7)) * 8)];
                bf[t] = *(const f16x8*)&Bs[Rb * 64 + (((kc * 4 + quad) ^ (Rb & 7)) * 8)];
            }
            #pragma unroll
            for (int i = 0; i < 4; ++i)
                #pragma unroll
                for (int j = 0; j < 4; ++j)
                    acc[i][j] = __builtin_amdgcn_mfma_f32_16x16x32_f16(af[i], bf[j], acc[i][j], 0, 0, 0);
        }
        __builtin_amdgcn_s_setprio(0);
        RAW_BAR();   // all waves done reading before next stage overwrites
    }

    // Epilogue: per-row reciprocal denominators via LDS broadcast, NT stores.
    if (tid < 128) rdI[tid] = 1.0f / denom[b * NN + I + tid];
    LGKM_BAR();

    #pragma unroll
    for (int i = 0; i < 4; ++i) {
        const int rowb = wr * 64 + i * 16 + quad * 4;
        #pragma unroll
        for (int r = 0; r < 4; ++r) {
            const float sc = rdI[rowb + r];
            float* op = out + ((size_t)(b * NN + I + rowb + r)) * DD + D0;
            #pragma unroll
            for (int j = 0; j < 4; ++j)
                __builtin_nontemporal_store(acc[i][j][r] * sc,
                                            op + wcol * 64 + j * 16 + m_);
        }
    }
}

// ---------------------------------------------------------------------------
extern "C" void kernel_launch(void* const* d_in, const int* in_sizes, int n_in,
                              void* d_out, int out_size, void* d_ws, size_t ws_size,
                              hipStream_t stream) {
    const float* x = (const float*)d_in[0];
    char* ws = (char*)d_ws;
    _Float16* xhn   = (_Float16*)(ws);                        // 32 MiB normalized fp16
    _Float16* vT    = (_Float16*)(ws + (size_t)33554432);     // 32 MiB fp16 x^T
    _Float16* W     = (_Float16*)(ws + (size_t)67108864);     // 128 MiB fp16 exp-scores
    float*    denom = (float*)   (ws + (size_t)201326592);    // 128 KiB
    float*    out   = (float*)d_out;

    k_prep<<<dim3(NN / 64, BB), 256, 0, stream>>>(x, xhn, vT, denom);
    const int npairs = (NN / 128) * (NN / 128 + 1) / 2;   // 136
    k_scores<<<dim3(npairs, 1, BB), 256, 0, stream>>>(xhn, W, denom);
    // 512 blocks = 2 blocks/CU (static 48.5 KiB LDS), XCD batch-pinned
    k_pv<<<dim3(512, 1, 1), 512, 0, stream>>>(W, vT, denom, out);
}